// Round 1
// baseline (529.470 us; speedup 1.0000x reference)
//
#include <hip/hip_runtime.h>

#define B  8
#define N  8192
#define M  2048
#define C  64
#define CT 64
#define K  32
#define R2 0.04f   // nearest f32 to 0.2*0.2, matches jnp/np promotion

// ---------------------------------------------------------------------------
// Kernel 1: ball query. One wave (64 lanes) per center. Lanes scan points in
// chunks of 64; __ballot + prefix-popcount assigns ordered slots so we keep
// the FIRST K valid points in original index order (PointNet++ semantics).
// Early exit once count >= K. Slots beyond count are filled with the first
// valid index (0 if the ball is empty).
// d2 replicates np: cn+pn-2*cross, sequential 3-term sums, NO fma contraction.
// ---------------------------------------------------------------------------
__global__ __launch_bounds__(256) void ball_query_kernel(
    const float* __restrict__ points,   // [B,3,N]
    const float* __restrict__ centers,  // [B,3,M]
    int* __restrict__ idx)              // [B,M,K]
{
    __shared__ int sidx[4][K];
    const int wave = threadIdx.x >> 6;
    const int lane = threadIdx.x & 63;
    const int center_id = blockIdx.x * 4 + wave;   // flat b*M+m
    const int b = center_id / M;
    const int m = center_id - b * M;

    const float* pc = points + b * 3 * N;
    const float cx = centers[(b * 3 + 0) * M + m];
    const float cy = centers[(b * 3 + 1) * M + m];
    const float cz = centers[(b * 3 + 2) * M + m];
    const float cn = __fadd_rn(__fadd_rn(__fmul_rn(cx, cx), __fmul_rn(cy, cy)),
                               __fmul_rn(cz, cz));

    if (lane == 0) sidx[wave][0] = 0;   // default fill when ball is empty

    int cnt = 0;
    for (int base = 0; base < N; base += 64) {
        const int n = base + lane;
        const float px = pc[n];
        const float py = pc[N + n];
        const float pz = pc[2 * N + n];
        const float pn = __fadd_rn(__fadd_rn(__fmul_rn(px, px), __fmul_rn(py, py)),
                                   __fmul_rn(pz, pz));
        const float cross = __fadd_rn(__fadd_rn(__fmul_rn(cx, px), __fmul_rn(cy, py)),
                                      __fmul_rn(cz, pz));
        const float d2 = __fsub_rn(__fadd_rn(cn, pn), __fmul_rn(2.0f, cross));
        const bool valid = d2 < R2;
        const unsigned long long mask = __ballot(valid);
        if (valid) {
            const int slot = cnt + __popcll(mask & ((1ull << lane) - 1ull));
            if (slot < K) sidx[wave][slot] = n;
        }
        cnt += (int)__popcll(mask);      // cnt is wave-uniform
        if (cnt >= K) break;             // uniform branch
    }
    __syncthreads();   // single barrier per block, outside the (uniform) loop

    if (lane < K) {
        const int fill = sidx[wave][0];        // first valid (or 0)
        const int v = sidx[wave][lane];
        idx[center_id * K + lane] = (lane < cnt) ? v : fill;
    }
}

// ---------------------------------------------------------------------------
// Kernel 2: grouped gather. 256 threads = 8 centers x 32 k-slots; for a fixed
// channel the block's 256 stores are one fully-contiguous 1 KB segment
// (m*K+k contiguous across the block). Gathered reads hit 32KB channel rows
// that are L1/L2 resident per batch.
// ---------------------------------------------------------------------------
__global__ __launch_bounds__(256) void gather_kernel(
    const float* __restrict__ points,    // [B,3,N]
    const float* __restrict__ centers,   // [B,3,M]
    const float* __restrict__ temb,      // [B,CT,N]
    const float* __restrict__ feats,     // [B,C,N]
    const int* __restrict__ idx,         // [B,M,K]
    float* __restrict__ out1,            // [B,3+C,M,K]
    float* __restrict__ out2)            // [B,CT,M,K]
{
    const int t = threadIdx.x;
    const int k = t & (K - 1);
    const int ml = t >> 5;                 // 0..7
    const int MB = M / 8;
    const int b = blockIdx.x / MB;
    const int m = (blockIdx.x - b * MB) * 8 + ml;

    const int n = idx[(b * M + m) * K + k];

    const float* pc = points + (size_t)b * 3 * N;
    const float* tf = temb + (size_t)b * CT * N;
    const float* ff = feats + (size_t)b * C * N;

    float* o1 = out1 + ((size_t)b * (3 + C) * M + m) * K + k;
    float* o2 = out2 + ((size_t)b * CT * M + m) * K + k;
    const size_t cs = (size_t)M * K;       // channel stride in outputs

    // neighbor coords, re-centered
    #pragma unroll
    for (int c = 0; c < 3; ++c) {
        const float ctr = centers[(b * 3 + c) * M + m];
        o1[(size_t)c * cs] = pc[c * N + n] - ctr;
    }
    // point features
    #pragma unroll 8
    for (int c = 0; c < C; ++c) {
        o1[(size_t)(3 + c) * cs] = ff[c * N + n];
    }
    // temb
    #pragma unroll 8
    for (int c = 0; c < CT; ++c) {
        o2[(size_t)c * cs] = tf[c * N + n];
    }
}

extern "C" void kernel_launch(void* const* d_in, const int* in_sizes, int n_in,
                              void* d_out, int out_size, void* d_ws, size_t ws_size,
                              hipStream_t stream) {
    const float* points  = (const float*)d_in[0];  // [8,3,8192]
    const float* centers = (const float*)d_in[1];  // [8,3,2048]
    const float* temb    = (const float*)d_in[2];  // [8,64,8192]
    const float* feats   = (const float*)d_in[3];  // [8,64,8192]

    int* idx = (int*)d_ws;                         // B*M*K*4 = 2 MB scratch
    float* out1 = (float*)d_out;                   // [8,67,2048,32]
    float* out2 = out1 + (size_t)B * (3 + C) * M * K;  // [8,64,2048,32]

    ball_query_kernel<<<(B * M) / 4, 256, 0, stream>>>(points, centers, idx);
    gather_kernel<<<(B * M) / 8, 256, 0, stream>>>(points, centers, temb, feats,
                                                   idx, out1, out2);
}

// Round 2
// 382.272 us; speedup vs baseline: 1.3851x; 1.3851x over previous
//
#include <hip/hip_runtime.h>

#define B  8
#define N  8192
#define M  2048
#define C  64
#define CT 64
#define K  32
#define R2 0.04f   // nearest f32 to 0.2*0.2, matches jnp/np promotion

// ---------------------------------------------------------------------------
// Kernel 0: transpose feats/temb [B,64,N] -> [B,N,64] and points [B,3,N] ->
// [B,N,4] so the gather kernel reads contiguous 256B rows per neighbor.
// 64x64 LDS tile transpose, coalesced both directions, stride-65 pad.
// ---------------------------------------------------------------------------
__global__ __launch_bounds__(256) void transpose_kernel(
    const float* __restrict__ points,   // [B,3,N]
    const float* __restrict__ temb,     // [B,CT,N]
    const float* __restrict__ feats,    // [B,C,N]
    float* __restrict__ pointsT,        // [B,N,4]
    float* __restrict__ tembT,          // [B,N,64]
    float* __restrict__ featsT)         // [B,N,64]
{
    const int gx = blockIdx.x;
    if (gx < 2048) {
        const int a  = gx >> 10;          // 0: feats, 1: temb
        const int tt = gx & 1023;         // b * 128 + tile
        const int b  = tt >> 7;
        const int n0 = (tt & 127) << 6;
        const float* src = (a ? temb : feats) + (size_t)b * 64 * N;
        float* dst = (a ? tembT : featsT) + (size_t)b * N * 64;
        __shared__ float lds[64][65];
        const int nl = threadIdx.x & 63;
        const int c0 = threadIdx.x >> 6;   // 0..3
        #pragma unroll
        for (int i = 0; i < 16; ++i) {
            const int c = c0 + i * 4;      // wave-uniform channel
            lds[c][nl] = src[(size_t)c * N + n0 + nl];
        }
        __syncthreads();
        #pragma unroll
        for (int i = 0; i < 16; ++i) {
            const int n = c0 + i * 4;      // wave-uniform point
            dst[(size_t)(n0 + n) * 64 + nl] = lds[nl][n];
        }
    } else {
        const int tt = gx - 2048;          // b * 32 + seg
        const int b  = tt >> 5;
        const int n  = ((tt & 31) << 8) + threadIdx.x;
        const float* pc = points + (size_t)b * 3 * N;
        float* dst = pointsT + ((size_t)b * N + n) * 4;
        dst[0] = pc[n];
        dst[1] = pc[N + n];
        dst[2] = pc[2 * N + n];
    }
}

// ---------------------------------------------------------------------------
// Kernel 1: ball query (unchanged from R1 — correct, and not yet proven to be
// the bottleneck; isolating the gather change this round).
// ---------------------------------------------------------------------------
__global__ __launch_bounds__(256) void ball_query_kernel(
    const float* __restrict__ points,   // [B,3,N]
    const float* __restrict__ centers,  // [B,3,M]
    int* __restrict__ idx)              // [B,M,K]
{
    __shared__ int sidx[4][K];
    const int wave = threadIdx.x >> 6;
    const int lane = threadIdx.x & 63;
    const int center_id = blockIdx.x * 4 + wave;
    const int b = center_id / M;
    const int m = center_id - b * M;

    const float* pc = points + b * 3 * N;
    const float cx = centers[(b * 3 + 0) * M + m];
    const float cy = centers[(b * 3 + 1) * M + m];
    const float cz = centers[(b * 3 + 2) * M + m];
    const float cn = __fadd_rn(__fadd_rn(__fmul_rn(cx, cx), __fmul_rn(cy, cy)),
                               __fmul_rn(cz, cz));

    if (lane == 0) sidx[wave][0] = 0;

    int cnt = 0;
    for (int base = 0; base < N; base += 64) {
        const int n = base + lane;
        const float px = pc[n];
        const float py = pc[N + n];
        const float pz = pc[2 * N + n];
        const float pn = __fadd_rn(__fadd_rn(__fmul_rn(px, px), __fmul_rn(py, py)),
                                   __fmul_rn(pz, pz));
        const float cross = __fadd_rn(__fadd_rn(__fmul_rn(cx, px), __fmul_rn(cy, py)),
                                      __fmul_rn(cz, pz));
        const float d2 = __fsub_rn(__fadd_rn(cn, pn), __fmul_rn(2.0f, cross));
        const bool valid = d2 < R2;
        const unsigned long long mask = __ballot(valid);
        if (valid) {
            const int slot = cnt + __popcll(mask & ((1ull << lane) - 1ull));
            if (slot < K) sidx[wave][slot] = n;
        }
        cnt += (int)__popcll(mask);
        if (cnt >= K) break;
    }
    __syncthreads();

    if (lane < K) {
        const int fill = sidx[wave][0];
        const int v = sidx[wave][lane];
        idx[center_id * K + lane] = (lane < cnt) ? v : fill;
    }
}

// ---------------------------------------------------------------------------
// Kernel 2: gather v2. Block = 4 centers = 128 (m,k) pairs.
// Reads: per pair one contiguous 256B row (float4 x 16 lanes) -> 16 lines per
// wave-inst instead of 64.  LDS tile (stride 65: all phases <=2-way banked)
// transposes pair-major -> channel-major.  Writes: 256B coalesced per inst.
// ---------------------------------------------------------------------------
__global__ __launch_bounds__(256) void gather_kernel(
    const float* __restrict__ pointsT,  // [B,N,4]
    const float* __restrict__ centers,  // [B,3,M]
    const float* __restrict__ tembT,    // [B,N,64]
    const float* __restrict__ featsT,   // [B,N,64]
    const int* __restrict__ idx,        // [B,M,K]
    float* __restrict__ out1,           // [B,3+C,M,K]
    float* __restrict__ out2)           // [B,CT,M,K]
{
    __shared__ int   sn[128];
    __shared__ float tile[128 * 65];
    __shared__ float ctile[3][128];

    const int t = threadIdx.x;
    const int MB4 = M / 4;
    const int b  = blockIdx.x / MB4;
    const int m0 = (blockIdx.x - b * MB4) * 4;
    const size_t base_mk = (size_t)m0 * K;
    const size_t cs = (size_t)M * K;

    if (t < 128) sn[t] = idx[((size_t)b * M + m0) * K + t];
    __syncthreads();

    const int cq = t & 15;     // float4 slot: channels cq*4 .. cq*4+3
    const int pl = t >> 4;     // 0..15: pair within iteration group
    const float* fT = featsT + (size_t)b * N * 64;
    const float* tT = tembT  + (size_t)b * N * 64;

    // ---- phase A: feats -> out1 channels 3..66 ----
    #pragma unroll
    for (int i = 0; i < 8; ++i) {
        const int p = i * 16 + pl;
        const int n = sn[p];
        const float4 v = *(const float4*)(fT + (size_t)n * 64 + cq * 4);
        float* d = &tile[p * 65 + cq * 4];
        d[0] = v.x; d[1] = v.y; d[2] = v.z; d[3] = v.w;
    }
    __syncthreads();
    {
        const int p   = t & 127;
        const int ch0 = t >> 7;    // 0..1
        float* o = out1 + (size_t)b * 67 * cs + 3 * cs + base_mk + p;
        #pragma unroll
        for (int i = 0; i < 32; ++i) {
            const int c = ch0 + i * 2;
            o[(size_t)c * cs] = tile[p * 65 + c];
        }
    }
    __syncthreads();

    // ---- phase B: temb -> out2 channels 0..63 ----
    #pragma unroll
    for (int i = 0; i < 8; ++i) {
        const int p = i * 16 + pl;
        const int n = sn[p];
        const float4 v = *(const float4*)(tT + (size_t)n * 64 + cq * 4);
        float* d = &tile[p * 65 + cq * 4];
        d[0] = v.x; d[1] = v.y; d[2] = v.z; d[3] = v.w;
    }
    __syncthreads();
    {
        const int p   = t & 127;
        const int ch0 = t >> 7;
        float* o = out2 + (size_t)b * 64 * cs + base_mk + p;
        #pragma unroll
        for (int i = 0; i < 32; ++i) {
            const int c = ch0 + i * 2;
            o[(size_t)c * cs] = tile[p * 65 + c];
        }
    }

    // ---- coords -> out1 channels 0..2 (re-centered) ----
    if (t < 128) {
        const int p = t;
        const int n = sn[p];
        const int m = m0 + (p >> 5);
        const float4 v = *(const float4*)(pointsT + ((size_t)b * N + n) * 4);
        ctile[0][p] = v.x - centers[((size_t)b * 3 + 0) * M + m];
        ctile[1][p] = v.y - centers[((size_t)b * 3 + 1) * M + m];
        ctile[2][p] = v.z - centers[((size_t)b * 3 + 2) * M + m];
    }
    __syncthreads();
    {
        const int c = t >> 7;      // 0..1
        const int p = t & 127;
        out1[((size_t)b * 67 + c) * cs + base_mk + p] = ctile[c][p];
    }
    if (t < 128) {
        out1[((size_t)b * 67 + 2) * cs + base_mk + t] = ctile[2][t];
    }
}

extern "C" void kernel_launch(void* const* d_in, const int* in_sizes, int n_in,
                              void* d_out, int out_size, void* d_ws, size_t ws_size,
                              hipStream_t stream) {
    const float* points  = (const float*)d_in[0];  // [8,3,8192]
    const float* centers = (const float*)d_in[1];  // [8,3,2048]
    const float* temb    = (const float*)d_in[2];  // [8,64,8192]
    const float* feats   = (const float*)d_in[3];  // [8,64,8192]

    // workspace layout (35 MB total)
    int*   idx     = (int*)d_ws;                              // 2 MB
    float* pointsT = (float*)((char*)d_ws + (2u << 20));      // 1 MB
    float* featsT  = pointsT + (size_t)B * N * 4;             // 16 MB
    float* tembT   = featsT  + (size_t)B * N * 64;            // 16 MB

    float* out1 = (float*)d_out;                              // [8,67,2048,32]
    float* out2 = out1 + (size_t)B * (3 + C) * M * K;         // [8,64,2048,32]

    transpose_kernel<<<2304, 256, 0, stream>>>(points, temb, feats,
                                               pointsT, tembT, featsT);
    ball_query_kernel<<<(B * M) / 4, 256, 0, stream>>>(points, centers, idx);
    gather_kernel<<<(B * M) / 4, 256, 0, stream>>>(pointsT, centers, tembT,
                                                   featsT, idx, out1, out2);
}

// Round 3
// 328.620 us; speedup vs baseline: 1.6112x; 1.1633x over previous
//
#include <hip/hip_runtime.h>

#define B  8
#define N  8192
#define M  2048
#define C  64
#define CT 64
#define K  32
#define R2 0.04f   // nearest f32 to 0.2*0.2, matches jnp/np promotion

// ---------------------------------------------------------------------------
// Kernel 0: transpose feats/temb [B,64,N] -> [B,N,64] and points [B,3,N] ->
// [B,N,4] so downstream reads are contiguous per neighbor.
// ---------------------------------------------------------------------------
__global__ __launch_bounds__(256) void transpose_kernel(
    const float* __restrict__ points,   // [B,3,N]
    const float* __restrict__ temb,     // [B,CT,N]
    const float* __restrict__ feats,    // [B,C,N]
    float* __restrict__ pointsT,        // [B,N,4]
    float* __restrict__ tembT,          // [B,N,64]
    float* __restrict__ featsT)         // [B,N,64]
{
    const int gx = blockIdx.x;
    if (gx < 2048) {
        const int a  = gx >> 10;          // 0: feats, 1: temb
        const int tt = gx & 1023;         // b * 128 + tile
        const int b  = tt >> 7;
        const int n0 = (tt & 127) << 6;
        const float* src = (a ? temb : feats) + (size_t)b * 64 * N;
        float* dst = (a ? tembT : featsT) + (size_t)b * N * 64;
        __shared__ float lds[64][65];
        const int nl = threadIdx.x & 63;
        const int c0 = threadIdx.x >> 6;   // 0..3
        #pragma unroll
        for (int i = 0; i < 16; ++i) {
            const int c = c0 + i * 4;
            lds[c][nl] = src[(size_t)c * N + n0 + nl];
        }
        __syncthreads();
        #pragma unroll
        for (int i = 0; i < 16; ++i) {
            const int n = c0 + i * 4;
            dst[(size_t)(n0 + n) * 64 + nl] = lds[nl][n];
        }
    } else {
        const int tt = gx - 2048;          // b * 32 + seg
        const int b  = tt >> 5;
        const int n  = ((tt & 31) << 8) + threadIdx.x;
        const float* pc = points + (size_t)b * 3 * N;
        float* dst = pointsT + ((size_t)b * N + n) * 4;
        dst[0] = pc[n];
        dst[1] = pc[N + n];
        dst[2] = pc[2 * N + n];
        dst[3] = 0.0f;
    }
}

// process one 64-point chunk: ballot + ordered slot assignment.
// d2 replicates np op order exactly: (cn+pn) - 2*cross, no fma contraction.
#define PROC(vv, nn)                                                          \
    do {                                                                      \
        const float px = (vv).x, py = (vv).y, pz = (vv).z;                    \
        const float pn2 = __fadd_rn(                                          \
            __fadd_rn(__fmul_rn(px, px), __fmul_rn(py, py)),                  \
            __fmul_rn(pz, pz));                                               \
        const float cross = __fadd_rn(                                        \
            __fadd_rn(__fmul_rn(cx, px), __fmul_rn(cy, py)),                  \
            __fmul_rn(cz, pz));                                               \
        const float d2 = __fsub_rn(__fadd_rn(cn, pn2),                        \
                                   __fmul_rn(2.0f, cross));                   \
        const bool valid = d2 < R2;                                           \
        const unsigned long long mask = __ballot(valid);                      \
        if (valid) {                                                          \
            const int slot = cnt + __builtin_amdgcn_mbcnt_hi(                 \
                (unsigned)(mask >> 32),                                       \
                __builtin_amdgcn_mbcnt_lo((unsigned)mask, 0));                \
            if (slot < K) sn[wv * K + slot] = (nn);                           \
        }                                                                     \
        cnt += (int)__popcll(mask);                                           \
    } while (0)

// ---------------------------------------------------------------------------
// Fused kernel: block = 4 centers, 256 threads = 4 waves.
// Phase 0 (per wave): ball query for its center. 512-point groups (8x float4,
//   full MLP) with ping-pong register prefetch; uniform break per group.
// Phase 1-3: LDS-transposed gather of feats/temb/coords, fully coalesced
//   stores (same structure as R2, sn now comes straight from LDS).
// ---------------------------------------------------------------------------
__global__ __launch_bounds__(256) void fused_kernel(
    const float* __restrict__ pointsT,  // [B,N,4]
    const float* __restrict__ centers,  // [B,3,M]
    const float* __restrict__ tembT,    // [B,N,64]
    const float* __restrict__ featsT,   // [B,N,64]
    float* __restrict__ out1,           // [B,3+C,M,K]
    float* __restrict__ out2)           // [B,CT,M,K]
{
    __shared__ int   sn[128];
    __shared__ float tile[128 * 65];
    __shared__ float ctile[3][128];

    const int t = threadIdx.x;
    const int MB4 = M / 4;
    const int b  = blockIdx.x / MB4;
    const int m0 = (blockIdx.x - b * MB4) * 4;
    const size_t base_mk = (size_t)m0 * K;
    const size_t cs = (size_t)M * K;

    // ---------------- phase 0: ball query, one wave per center -------------
    {
        const int wv   = t >> 6;
        const int lane = t & 63;
        const int m    = m0 + wv;
        const float cx = centers[((size_t)b * 3 + 0) * M + m];
        const float cy = centers[((size_t)b * 3 + 1) * M + m];
        const float cz = centers[((size_t)b * 3 + 2) * M + m];
        const float cn = __fadd_rn(
            __fadd_rn(__fmul_rn(cx, cx), __fmul_rn(cy, cy)),
            __fmul_rn(cz, cz));

        if (lane == 0) sn[wv * K] = 0;   // default fill for empty ball

        const float4* pt4 = (const float4*)(pointsT + (size_t)b * N * 4);
        int cnt = 0;
        float4 va[8], vb[8];
        #pragma unroll
        for (int j = 0; j < 8; ++j) va[j] = pt4[j * 64 + lane];

        for (int g = 0; g < 16; g += 2) {
            if (g + 1 < 16) {
                #pragma unroll
                for (int j = 0; j < 8; ++j)
                    vb[j] = pt4[((g + 1) * 8 + j) * 64 + lane];
            }
            #pragma unroll
            for (int j = 0; j < 8; ++j) PROC(va[j], g * 512 + j * 64 + lane);
            if (cnt >= K || g + 1 >= 16) break;

            if (g + 2 < 16) {
                #pragma unroll
                for (int j = 0; j < 8; ++j)
                    va[j] = pt4[((g + 2) * 8 + j) * 64 + lane];
            }
            #pragma unroll
            for (int j = 0; j < 8; ++j) PROC(vb[j], (g + 1) * 512 + j * 64 + lane);
            if (cnt >= K) break;
        }

        // fill slots >= cnt with first valid index (wave-internal, ordered)
        if (lane < K) {
            const int fill = sn[wv * K];
            const int v    = sn[wv * K + lane];
            sn[wv * K + lane] = (lane < cnt) ? v : fill;
        }
    }
    __syncthreads();

    const int cq = t & 15;     // float4 slot: channels cq*4 .. cq*4+3
    const int pl = t >> 4;     // 0..15
    const float* fT = featsT + (size_t)b * N * 64;
    const float* tT = tembT  + (size_t)b * N * 64;

    // ---- phase 1: feats -> out1 channels 3..66 ----
    #pragma unroll
    for (int i = 0; i < 8; ++i) {
        const int p = i * 16 + pl;
        const int n = sn[p];
        const float4 v = *(const float4*)(fT + (size_t)n * 64 + cq * 4);
        float* d = &tile[p * 65 + cq * 4];
        d[0] = v.x; d[1] = v.y; d[2] = v.z; d[3] = v.w;
    }
    __syncthreads();
    {
        const int p   = t & 127;
        const int ch0 = t >> 7;    // 0..1
        float* o = out1 + (size_t)b * 67 * cs + 3 * cs + base_mk + p;
        #pragma unroll
        for (int i = 0; i < 32; ++i) {
            const int c = ch0 + i * 2;
            o[(size_t)c * cs] = tile[p * 65 + c];
        }
    }
    __syncthreads();

    // ---- phase 2: temb -> out2 channels 0..63 ----
    #pragma unroll
    for (int i = 0; i < 8; ++i) {
        const int p = i * 16 + pl;
        const int n = sn[p];
        const float4 v = *(const float4*)(tT + (size_t)n * 64 + cq * 4);
        float* d = &tile[p * 65 + cq * 4];
        d[0] = v.x; d[1] = v.y; d[2] = v.z; d[3] = v.w;
    }
    __syncthreads();
    {
        const int p   = t & 127;
        const int ch0 = t >> 7;
        float* o = out2 + (size_t)b * 64 * cs + base_mk + p;
        #pragma unroll
        for (int i = 0; i < 32; ++i) {
            const int c = ch0 + i * 2;
            o[(size_t)c * cs] = tile[p * 65 + c];
        }
    }

    // ---- phase 3: coords -> out1 channels 0..2 (re-centered) ----
    if (t < 128) {
        const int p = t;
        const int n = sn[p];
        const int m = m0 + (p >> 5);
        const float4 v = *(const float4*)(pointsT + ((size_t)b * N + n) * 4);
        ctile[0][p] = v.x - centers[((size_t)b * 3 + 0) * M + m];
        ctile[1][p] = v.y - centers[((size_t)b * 3 + 1) * M + m];
        ctile[2][p] = v.z - centers[((size_t)b * 3 + 2) * M + m];
    }
    __syncthreads();
    {
        const int c = t >> 7;      // 0..1
        const int p = t & 127;
        out1[((size_t)b * 67 + c) * cs + base_mk + p] = ctile[c][p];
    }
    if (t < 128) {
        out1[((size_t)b * 67 + 2) * cs + base_mk + t] = ctile[2][t];
    }
}

extern "C" void kernel_launch(void* const* d_in, const int* in_sizes, int n_in,
                              void* d_out, int out_size, void* d_ws, size_t ws_size,
                              hipStream_t stream) {
    const float* points  = (const float*)d_in[0];  // [8,3,8192]
    const float* centers = (const float*)d_in[1];  // [8,3,2048]
    const float* temb    = (const float*)d_in[2];  // [8,64,8192]
    const float* feats   = (const float*)d_in[3];  // [8,64,8192]

    // workspace layout (33 MB)
    float* pointsT = (float*)d_ws;                            // 1 MB
    float* featsT  = pointsT + (size_t)B * N * 4;             // 16 MB
    float* tembT   = featsT  + (size_t)B * N * 64;            // 16 MB

    float* out1 = (float*)d_out;                              // [8,67,2048,32]
    float* out2 = out1 + (size_t)B * (3 + C) * M * K;         // [8,64,2048,32]

    transpose_kernel<<<2304, 256, 0, stream>>>(points, temb, feats,
                                               pointsT, tembT, featsT);
    fused_kernel<<<(B * M) / 4, 256, 0, stream>>>(pointsT, centers, tembT,
                                                  featsT, out1, out2);
}